// Round 2
// baseline (398.108 us; speedup 1.0000x reference)
//
#include <hip/hip_runtime.h>
#include <stdint.h>

#define Bn 2
#define Nn 30000
#define En 120000
#define KIN 512
#define Hh 4
#define Dd 128
#define MROWS 60000            // B*N rows
#define MPAD  60032            // 469 * 128
#define LNEPS 1e-5f
#define EBLK 469               // ceil(En/256)

typedef unsigned short u16;
typedef unsigned int   u32;
typedef __attribute__((ext_vector_type(8))) short short8;
typedef __attribute__((ext_vector_type(4))) float f32x4;

__device__ __forceinline__ u16 f2bf(float f) {
    u32 u = __builtin_bit_cast(u32, f);
    u32 r = u + 0x7FFFu + ((u >> 16) & 1u);
    return (u16)(r >> 16);
}
__device__ __forceinline__ float bflo(u32 u) {
    return __builtin_bit_cast(float, u << 16);
}
__device__ __forceinline__ float bfhi(u32 u) {
    return __builtin_bit_cast(float, u & 0xFFFF0000u);
}
__device__ __forceinline__ void ld16(void* lds, const void* g) {
    __builtin_amdgcn_global_load_lds((const __attribute__((address_space(1))) void*)g,
                                     (__attribute__((address_space(3))) void*)lds, 16, 0, 0);
}

// ---- kernel 1: prep = cvt_x (15008 blocks) + cvt_w (1024) + hist (469) ----
#define CVTX_BLKS 15008        // MPAD*KIN/8/256 exactly
#define CVTW_BLKS 1024         // 512*512/256 exactly
__global__ void prep_kernel(const float* __restrict__ x, u16* __restrict__ xb,
                            const float* __restrict__ W, u16* __restrict__ wbt,
                            const int* __restrict__ ei, int* __restrict__ deg) {
    int blk = blockIdx.x;
    if (blk < CVTX_BLKS) {
        long base = ((long)blk * 256 + threadIdx.x) * 8;
        short8 o = {};
        if (base < (long)MROWS * KIN) {
            const float4* px = (const float4*)(x + base);
            float4 v0 = px[0], v1 = px[1];
            o[0] = (short)f2bf(v0.x); o[1] = (short)f2bf(v0.y);
            o[2] = (short)f2bf(v0.z); o[3] = (short)f2bf(v0.w);
            o[4] = (short)f2bf(v1.x); o[5] = (short)f2bf(v1.y);
            o[6] = (short)f2bf(v1.z); o[7] = (short)f2bf(v1.w);
        }
        *(short8*)(xb + base) = o;
    } else if (blk < CVTX_BLKS + CVTW_BLKS) {
        int idx = (blk - CVTX_BLKS) * 256 + threadIdx.x;
        int c = idx >> 9, i = idx & 511;
        int h = c >> 7, d = c & 127;
        wbt[idx] = f2bf(W[h * (KIN * Dd) + i * Dd + d]);
    } else {
        int e = (blk - CVTX_BLKS - CVTW_BLKS) * 256 + threadIdx.x;
        if (e < En) atomicAdd(&deg[ei[En + e]], 1);
    }
}

// ---- scan as a device function: 512 threads, exclusive scan of deg[30000].
//      part[] lives in the caller's (gemm) LDS block: keeps gemm at exactly
//      80 KB static LDS -> 2 blocks/CU. ----
__device__ void scan512(const int* __restrict__ deg, int* __restrict__ offs,
                        int* __restrict__ cursor, int* __restrict__ part) {
    int tid = threadIdx.x;
    const int CH = 59;                 // 512*59 = 30208 >= Nn
    int start = tid * CH;
    int s = 0;
    for (int i = 0; i < CH; i++) {
        int n = start + i;
        if (n < Nn) s += deg[n];
    }
    part[tid] = s;
    __syncthreads();
    for (int off = 1; off < 512; off <<= 1) {
        int xv = (tid >= off) ? part[tid - off] : 0;
        __syncthreads();
        part[tid] += xv;
        __syncthreads();
    }
    int run = part[tid] - s;
    for (int i = 0; i < CH; i++) {
        int n = start + i;
        if (n < Nn) {
            offs[n] = run;
            cursor[n] = run;
            run += deg[n];
        }
    }
    if (tid == 511) offs[Nn] = part[511];
}

// ---- kernel 2: GEMM t = xb * wbt^T, BN=512 single pass (A staged ONCE),
//      2-phase prefetch (1 barrier/K-step), XOR-swizzled LDS (T2, rule #21).
//      LDS = exactly 80 KB (As 16K + Bs 64K, scan reuses it) -> 2 blocks/CU,
//      all 470 blocks co-resident in ONE grid round; cross-block overlap
//      hides the per-step vmcnt(0) drain (m114 mechanism).
//      8 waves: wave w -> rows (w>>2)*64..+63, head w&3 (cols h*128..+127).
//      Fused s1/s2 epilogue per wave; block 0 hosts the prefix scan. ----
#define A_LDS (2 * 128 * 32)
#define B_LDS (2 * 512 * 32)
__launch_bounds__(512)
__global__ void gemm(const u16* __restrict__ xb, const u16* __restrict__ wbt,
                     const float* __restrict__ ag, u16* __restrict__ t,
                     float* __restrict__ s1g, float* __restrict__ s2g,
                     const int* __restrict__ deg, int* __restrict__ offs,
                     int* __restrict__ cursor) {
    __shared__ __align__(16) u16 smem[A_LDS + B_LDS];   // 80 KB exactly
    if (blockIdx.x == 0) { scan512(deg, offs, cursor, (int*)smem); return; }
    u16* As0 = smem;
    u16* As1 = smem + 128 * 32;
    u16* Bs0 = smem + A_LDS;
    u16* Bs1 = smem + A_LDS + 512 * 32;
    const int tid = threadIdx.x;
    const int m0 = (blockIdx.x - 1) * 128;          // tiles 0..468
    const int w = tid >> 6, l = tid & 63;
    const int lr = l & 15, lk = l >> 4;
    const int wrM = (w >> 2) * 64;                  // wave row base
    const int h = w & 3;                            // wave head
    const int wc = h * 128;                         // wave col base
    // swizzled ds_read offsets (u16 units): byte ^= ((row&6)<<3) on the 16B slot
    const int swz = (lk * 8) ^ ((lr & 6) << 2);
    int aoff[4], boff[8];
    #pragma unroll
    for (int mi = 0; mi < 4; mi++) aoff[mi] = (wrM + mi * 16 + lr) * 32 + swz;
    #pragma unroll
    for (int nj = 0; nj < 8; nj++) boff[nj] = (wc + nj * 16 + lr) * 32 + swz;

    // pre-swizzled global sources (inverse of the read swizzle; involution)
    const int grow = tid >> 2, gslot = tid & 3;
    const int gsw = (gslot * 8) ^ ((grow & 6) << 2);
    const u16* agsrc = xb + (long)(m0 + grow) * KIN + gsw;   // A chunk = tid
    const u16* bgsrc = wbt + (long)grow * KIN + gsw;         // B chunk i = i*512+tid
                                                             // (row += i*128: row&6 unchanged)
    f32x4 acc[4][8] = {};

    auto STAGE = [&](u16* Ab, u16* Bb, int k0) {
        ld16(Ab + (long)tid * 8, agsrc + k0);
        #pragma unroll
        for (int i = 0; i < 4; i++)
            ld16(Bb + ((long)(i * 512 + tid)) * 8, bgsrc + (long)i * 128 * KIN + k0);
    };

    STAGE(As0, Bs0, 0);
    __syncthreads();                                // vmcnt(0) drain + barrier
    #pragma unroll 2
    for (int t16 = 0; t16 < 16; t16++) {
        u16* Ac = (t16 & 1) ? As1 : As0;
        u16* Bc = (t16 & 1) ? Bs1 : Bs0;
        if (t16 < 15)
            STAGE((t16 & 1) ? As0 : As1, (t16 & 1) ? Bs0 : Bs1, (t16 + 1) * 32);
        short8 af[4];
        #pragma unroll
        for (int mi = 0; mi < 4; mi++) af[mi] = *(const short8*)&Ac[aoff[mi]];
        #pragma unroll
        for (int nj = 0; nj < 8; nj++) {
            short8 bv = *(const short8*)&Bc[boff[nj]];
            #pragma unroll
            for (int mi = 0; mi < 4; mi++)
                acc[mi][nj] = __builtin_amdgcn_mfma_f32_16x16x32_bf16(
                    af[mi], bv, acc[mi][nj], 0, 0, 0);
        }
        __syncthreads();    // drains this step's prefetch + protects buffer reuse
    }
    // C/D map: col = wc + nj*16 + lr, row = wrM + mi*16 + lk*4 + r
    #pragma unroll
    for (int mi = 0; mi < 4; mi++)
        #pragma unroll
        for (int r = 0; r < 4; r++) {
            int row = m0 + wrM + mi * 16 + lk * 4 + r;
            u16* tp = t + (long)row * 512 + wc + lr;
            #pragma unroll
            for (int nj = 0; nj < 8; nj++)
                tp[nj * 16] = f2bf(acc[mi][nj][r]);
        }
    // ---- fused s1/s2: each wave covers one full head -> 16-lane reduce, direct store
    float a1c[8], a2c[8];
    #pragma unroll
    for (int nj = 0; nj < 8; nj++) {
        int col = nj * 16 + lr;
        a1c[nj] = ag[h * 256 + col];
        a2c[nj] = ag[h * 256 + 128 + col];
    }
    float p1[16], p2[16];
    #pragma unroll
    for (int mi = 0; mi < 4; mi++)
        #pragma unroll
        for (int r = 0; r < 4; r++) {
            float v1 = 0.f, v2 = 0.f;
            #pragma unroll
            for (int nj = 0; nj < 8; nj++) {
                float tv = acc[mi][nj][r];
                v1 += tv * a1c[nj];
                v2 += tv * a2c[nj];
            }
            p1[mi * 4 + r] = v1;
            p2[mi * 4 + r] = v2;
        }
    #pragma unroll
    for (int off = 1; off < 16; off <<= 1)
        #pragma unroll
        for (int i = 0; i < 16; i++) {
            p1[i] += __shfl_xor(p1[i], off, 64);
            p2[i] += __shfl_xor(p2[i], off, 64);
        }
    if (lr == 0) {
        #pragma unroll
        for (int mi = 0; mi < 4; mi++)
            #pragma unroll
            for (int r = 0; r < 4; r++) {
                int row = m0 + wrM + mi * 16 + lk * 4 + r;
                if (row < MROWS) {
                    s1g[(long)row * 4 + h] = p1[mi * 4 + r];
                    s2g[(long)row * 4 + h] = p2[mi * 4 + r];
                }
            }
    }
}

// ---- kernel 3: fused edge pass: score + leaky + exp (no shift; scores |s|<~10)
//      + dst-sorted scatter of srcs/pw + Z block partials, both batches ----
__global__ void edgescatter_kernel(const int* __restrict__ ei, const float* __restrict__ s1,
                                   const float* __restrict__ s2, int* __restrict__ cursor,
                                   int* __restrict__ srcs, float* __restrict__ pw,
                                   float* __restrict__ Zpart) {
    int e = blockIdx.x * 256 + threadIdx.x;
    int tid = threadIdx.x;
    float v[8] = {0.f, 0.f, 0.f, 0.f, 0.f, 0.f, 0.f, 0.f};
    if (e < En) {
        int src = ei[e], dst = ei[En + e];
        #pragma unroll
        for (int b = 0; b < Bn; b++) {
            float4 v1 = *(const float4*)(s1 + ((long)b * Nn + src) * 4);
            float4 v2 = *(const float4*)(s2 + ((long)b * Nn + dst) * 4);
            float s;
            s = v1.x + v2.x; s = s > 0.f ? s : 0.2f * s; v[b * 4 + 0] = __expf(s);
            s = v1.y + v2.y; s = s > 0.f ? s : 0.2f * s; v[b * 4 + 1] = __expf(s);
            s = v1.z + v2.z; s = s > 0.f ? s : 0.2f * s; v[b * 4 + 2] = __expf(s);
            s = v1.w + v2.w; s = s > 0.f ? s : 0.2f * s; v[b * 4 + 3] = __expf(s);
        }
        int pos = atomicAdd(&cursor[dst], 1);
        srcs[pos] = src;
        *(float4*)(pw + (long)pos * 4)        = make_float4(v[0], v[1], v[2], v[3]);
        *(float4*)(pw + ((long)En + pos) * 4) = make_float4(v[4], v[5], v[6], v[7]);
    }
    #pragma unroll
    for (int off = 1; off < 64; off <<= 1)
        #pragma unroll
        for (int i = 0; i < 8; i++)
            v[i] += __shfl_xor(v[i], off, 64);
    __shared__ float red[4][8];
    if ((tid & 63) == 0)
        #pragma unroll
        for (int i = 0; i < 8; i++)
            red[tid >> 6][i] = v[i];
    __syncthreads();
    if (tid < 8)
        Zpart[(long)blockIdx.x * 8 + tid] =
            red[0][tid] + red[1][tid] + red[2][tid] + red[3][tid];
}

// ---- kernel 4: reduce Z partials -> invZ[b*4+h] (256 thr = 8 groups x 32 lanes) ----
__global__ void zreduce_kernel(const float* __restrict__ Zpart, float* __restrict__ invZ) {
    int tid = threadIdx.x;
    int g = tid >> 5, l = tid & 31;
    float s = 0.f;
    for (int i = l; i < EBLK; i += 32)
        s += Zpart[(long)i * 8 + g];
    #pragma unroll
    for (int off = 1; off < 32; off <<= 1)
        s += __shfl_xor(s, off, 64);   // off<32 stays within the 32-lane half
    if (l == 0) invZ[g] = 1.0f / s;
}

// ---- kernel 5: aggregation (no atomics, 2-deep chain, x4 unrolled MLP) + fused LN ----
__launch_bounds__(128)
__global__ void agg_kernel(const u16* __restrict__ t, const int* __restrict__ srcs,
                           const float* __restrict__ pw, const float* __restrict__ invZ,
                           const int* __restrict__ offs,
                           const float* __restrict__ gamma, const float* __restrict__ beta,
                           float* __restrict__ out) {
    int tid = threadIdx.x;               // owns cols 4*tid .. 4*tid+3
    int n = blockIdx.x;
    int b = blockIdx.y;
    int h = tid >> 5;
    int j0 = offs[n], j1 = offs[n + 1];
    const float* pwb = pw + (long)b * En * 4;
    const u16* tb = t + (long)b * Nn * 512;
    float a0 = 0.f, a1 = 0.f, a2 = 0.f, a3 = 0.f;
    int j = j0;
    for (; j + 4 <= j1; j += 4) {
        int s0 = srcs[j], s1i = srcs[j + 1], s2i = srcs[j + 2], s3i = srcs[j + 3];
        float w0 = pwb[(long)j * 4 + h];
        float w1 = pwb[(long)(j + 1) * 4 + h];
        float w2 = pwb[(long)(j + 2) * 4 + h];
        float w3 = pwb[(long)(j + 3) * 4 + h];
        uint2 r0 = *(const uint2*)(tb + (long)s0 * 512 + tid * 4);
        uint2 r1 = *(const uint2*)(tb + (long)s1i * 512 + tid * 4);
        uint2 r2 = *(const uint2*)(tb + (long)s2i * 512 + tid * 4);
        uint2 r3 = *(const uint2*)(tb + (long)s3i * 512 + tid * 4);
        a0 += w0 * bflo(r0.x) + w1 * bflo(r1.x) + w2 * bflo(r2.x) + w3 * bflo(r3.x);
        a1 += w0 * bfhi(r0.x) + w1 * bfhi(r1.x) + w2 * bfhi(r2.x) + w3 * bfhi(r3.x);
        a2 += w0 * bflo(r0.y) + w1 * bflo(r1.y) + w2 * bflo(r2.y) + w3 * bflo(r3.y);
        a3 += w0 * bfhi(r0.y) + w1 * bfhi(r1.y) + w2 * bfhi(r2.y) + w3 * bfhi(r3.y);
    }
    for (; j < j1; j++) {
        int s0 = srcs[j];
        float w0 = pwb[(long)j * 4 + h];
        uint2 r0 = *(const uint2*)(tb + (long)s0 * 512 + tid * 4);
        a0 += w0 * bflo(r0.x);
        a1 += w0 * bfhi(r0.x);
        a2 += w0 * bflo(r0.y);
        a3 += w0 * bfhi(r0.y);
    }
    float invz = invZ[b * 4 + h];
    a0 *= invz; a1 *= invz; a2 *= invz; a3 *= invz;
    // fused LayerNorm over this node's 512 cols (128 threads = 2 waves)
    float s  = a0 + a1 + a2 + a3;
    float ss = a0 * a0 + a1 * a1 + a2 * a2 + a3 * a3;
    #pragma unroll
    for (int off = 1; off < 64; off <<= 1) {
        s  += __shfl_xor(s, off, 64);
        ss += __shfl_xor(ss, off, 64);
    }
    __shared__ float red[2][2];
    int wv = tid >> 6;
    if ((tid & 63) == 0) { red[wv][0] = s; red[wv][1] = ss; }
    __syncthreads();
    s  = red[0][0] + red[1][0];
    ss = red[0][1] + red[1][1];
    float mean = s * (1.0f / 512.0f);
    float var = ss * (1.0f / 512.0f) - mean * mean;
    var = var < 0.f ? 0.f : var;
    float scale = rsqrtf(var + LNEPS);
    int c = tid * 4;
    float4 o;
    o.x = (a0 - mean) * scale * gamma[c + 0] + beta[c + 0];
    o.y = (a1 - mean) * scale * gamma[c + 1] + beta[c + 1];
    o.z = (a2 - mean) * scale * gamma[c + 2] + beta[c + 2];
    o.w = (a3 - mean) * scale * gamma[c + 3] + beta[c + 3];
    *(float4*)(out + ((long)b * Nn + n) * 512 + c) = o;
}

extern "C" void kernel_launch(void* const* d_in, const int* in_sizes, int n_in,
                              void* d_out, int out_size, void* d_ws, size_t ws_size,
                              hipStream_t stream) {
    const float* x     = (const float*)d_in[0];
    const int*   ei    = (const int*)d_in[1];   // (2,E) int32
    const float* W     = (const float*)d_in[2];
    const float* a     = (const float*)d_in[3];
    const float* gamma = (const float*)d_in[4];
    const float* beta  = (const float*)d_in[5];
    float* out = (float*)d_out;

    char* ws = (char*)d_ws;
    size_t off = 0;
    auto alloc = [&](size_t bytes) -> void* {
        void* ptr = ws + off;
        off = (off + bytes + 255) & ~(size_t)255;
        return ptr;
    };
    u16*   xb     = (u16*)alloc((size_t)MPAD * KIN * 2);       // 61.5 MB
    u16*   wbt    = (u16*)alloc((size_t)512 * 512 * 2);        // 0.5 MB
    u16*   t      = (u16*)alloc((size_t)MPAD * 512 * 2);       // 61.5 MB
    float* s1     = (float*)alloc((size_t)MROWS * 4 * 4);
    float* s2     = (float*)alloc((size_t)MROWS * 4 * 4);
    float* pw     = (float*)alloc((size_t)Bn * En * 4 * 4);    // dst-sorted numerators
    float* Zpart  = (float*)alloc((size_t)EBLK * 8 * 4);
    float* invZ   = (float*)alloc(8 * 4);
    int*   deg    = (int*)alloc((size_t)Nn * 4);
    int*   offs   = (int*)alloc((size_t)(Nn + 1) * 4);
    int*   cursor = (int*)alloc((size_t)Nn * 4);
    int*   srcs   = (int*)alloc((size_t)En * 4);

    hipMemsetAsync(deg, 0, (size_t)Nn * 4, stream);

    prep_kernel<<<CVTX_BLKS + CVTW_BLKS + EBLK, 256, 0, stream>>>(x, xb, W, wbt, ei, deg);
    gemm<<<470, 512, 0, stream>>>(xb, wbt, a, t, s1, s2, deg, offs, cursor);
    edgescatter_kernel<<<EBLK, 256, 0, stream>>>(ei, s1, s2, cursor, srcs, pw, Zpart);
    zreduce_kernel<<<1, 256, 0, stream>>>(Zpart, invZ);
    agg_kernel<<<dim3(Nn, Bn), 128, 0, stream>>>(t, srcs, pw, invZ, offs, gamma, beta, out);
}

// Round 3
// 396.385 us; speedup vs baseline: 1.0043x; 1.0043x over previous
//
#include <hip/hip_runtime.h>
#include <stdint.h>

#define Bn 2
#define Nn 30000
#define En 120000
#define KIN 512
#define Hh 4
#define Dd 128
#define MROWS 60000            // B*N rows
#define MPAD  60032            // 469 * 128
#define LNEPS 1e-5f
#define EBLK 469               // ceil(En/256)

typedef unsigned short u16;
typedef unsigned int   u32;
typedef __attribute__((ext_vector_type(8))) short short8;
typedef __attribute__((ext_vector_type(4))) float f32x4;

__device__ __forceinline__ u16 f2bf(float f) {
    u32 u = __builtin_bit_cast(u32, f);
    u32 r = u + 0x7FFFu + ((u >> 16) & 1u);
    return (u16)(r >> 16);
}
__device__ __forceinline__ float bflo(u32 u) {
    return __builtin_bit_cast(float, u << 16);
}
__device__ __forceinline__ float bfhi(u32 u) {
    return __builtin_bit_cast(float, u & 0xFFFF0000u);
}

// ---- kernel 1: prep = cvt_x (15008 blocks) + cvt_w (1024) + hist (469) ----
#define CVTX_BLKS 15008        // MPAD*KIN/8/256 exactly
#define CVTW_BLKS 1024         // 512*512/256 exactly
__global__ void prep_kernel(const float* __restrict__ x, u16* __restrict__ xb,
                            const float* __restrict__ W, u16* __restrict__ wbt,
                            const int* __restrict__ ei, int* __restrict__ deg) {
    int blk = blockIdx.x;
    if (blk < CVTX_BLKS) {
        long base = ((long)blk * 256 + threadIdx.x) * 8;
        short8 o = {};
        if (base < (long)MROWS * KIN) {
            const float4* px = (const float4*)(x + base);
            float4 v0 = px[0], v1 = px[1];
            o[0] = (short)f2bf(v0.x); o[1] = (short)f2bf(v0.y);
            o[2] = (short)f2bf(v0.z); o[3] = (short)f2bf(v0.w);
            o[4] = (short)f2bf(v1.x); o[5] = (short)f2bf(v1.y);
            o[6] = (short)f2bf(v1.z); o[7] = (short)f2bf(v1.w);
        }
        *(short8*)(xb + base) = o;
    } else if (blk < CVTX_BLKS + CVTW_BLKS) {
        int idx = (blk - CVTX_BLKS) * 256 + threadIdx.x;
        int c = idx >> 9, i = idx & 511;
        int h = c >> 7, d = c & 127;
        wbt[idx] = f2bf(W[h * (KIN * Dd) + i * Dd + d]);
    } else {
        int e = (blk - CVTX_BLKS - CVTW_BLKS) * 256 + threadIdx.x;
        if (e < En) atomicAdd(&deg[ei[En + e]], 1);
    }
}

// ---- scan as a device function: 512 threads, exclusive scan of deg[30000] ----
__device__ void scan512(const int* __restrict__ deg, int* __restrict__ offs,
                        int* __restrict__ cursor) {
    __shared__ int part[512];
    int tid = threadIdx.x;
    const int CH = 59;                 // 512*59 = 30208 >= Nn
    int start = tid * CH;
    int s = 0;
    for (int i = 0; i < CH; i++) {
        int n = start + i;
        if (n < Nn) s += deg[n];
    }
    part[tid] = s;
    __syncthreads();
    for (int off = 1; off < 512; off <<= 1) {
        int xv = (tid >= off) ? part[tid - off] : 0;
        __syncthreads();
        part[tid] += xv;
        __syncthreads();
    }
    int run = part[tid] - s;
    for (int i = 0; i < CH; i++) {
        int n = start + i;
        if (n < Nn) {
            offs[n] = run;
            cursor[n] = run;
            run += deg[n];
        }
    }
    if (tid == 511) offs[Nn] = part[511];
}

// ---- kernel 2: GEMM t = xb * wbt^T, NO-LDS barrier-free dataflow.
//      MFMA fragments load DIRECTLY from global (A: 16 rows x 64 B contiguous
//      per instr; B is 512 KB, L2-resident). Zero barriers / zero vmcnt(0)
//      drains in the K-loop -> waves slip freely; compiler emits counted
//      vmcnt waits (m131 mechanism). Manual 2-stage pipeline with STATIC
//      register sets (rule #20). A re-read 4x across heads = L2 hits.
//      8 waves: wave w -> rows (w>>2)*64..+63, head w&3 (cols h*128..+127).
//      Fused s1/s2 epilogue per wave; block 0 hosts the prefix scan. ----
__launch_bounds__(512, 2)
__global__ void gemm(const u16* __restrict__ xb, const u16* __restrict__ wbt,
                     const float* __restrict__ ag, u16* __restrict__ t,
                     float* __restrict__ s1g, float* __restrict__ s2g,
                     const int* __restrict__ deg, int* __restrict__ offs,
                     int* __restrict__ cursor) {
    if (blockIdx.x == 0) { scan512(deg, offs, cursor); return; }
    const int tid = threadIdx.x;
    const int m0 = (blockIdx.x - 1) * 128;          // tiles 0..468
    const int w = tid >> 6, l = tid & 63;
    const int lr = l & 15, lk = l >> 4;
    const int wrM = (w >> 2) * 64;                  // wave row base
    const int h = w & 3;                            // wave head
    const int wc = h * 128;                         // wave col base

    // per-lane fragment base pointers (k advances via compile-time offsets)
    const u16* abase[4];
    const u16* bbase[8];
    #pragma unroll
    for (int mi = 0; mi < 4; mi++)
        abase[mi] = xb + (long)(m0 + wrM + mi * 16 + lr) * KIN + lk * 8;
    #pragma unroll
    for (int nj = 0; nj < 8; nj++)
        bbase[nj] = wbt + (long)(wc + nj * 16 + lr) * KIN + lk * 8;

    f32x4 acc[4][8] = {};
    short8 afA[4], bfA[8], afB[4], bfB[8];

#define LOADF(AF, BF, KS)                                           \
    {                                                               \
        _Pragma("unroll")                                           \
        for (int mi = 0; mi < 4; mi++)                              \
            AF[mi] = *(const short8*)(abase[mi] + (KS) * 32);       \
        _Pragma("unroll")                                           \
        for (int nj = 0; nj < 8; nj++)                              \
            BF[nj] = *(const short8*)(bbase[nj] + (KS) * 32);       \
    }
#define MFMAF(AF, BF)                                               \
    {                                                               \
        _Pragma("unroll")                                           \
        for (int nj = 0; nj < 8; nj++)                              \
            _Pragma("unroll")                                       \
            for (int mi = 0; mi < 4; mi++)                          \
                acc[mi][nj] = __builtin_amdgcn_mfma_f32_16x16x32_bf16( \
                    AF[mi], BF[nj], acc[mi][nj], 0, 0, 0);          \
    }

    LOADF(afA, bfA, 0);
    #pragma unroll
    for (int t16 = 0; t16 < 16; t16 += 2) {
        LOADF(afB, bfB, t16 + 1);       // issue next-step loads (independent)
        MFMAF(afA, bfA);                // compute current (hides B-load latency)
        if (t16 < 14) LOADF(afA, bfA, t16 + 2);
        MFMAF(afB, bfB);
    }
#undef LOADF
#undef MFMAF

    // C/D map: col = wc + nj*16 + lr, row = wrM + mi*16 + lk*4 + r
    #pragma unroll
    for (int mi = 0; mi < 4; mi++)
        #pragma unroll
        for (int r = 0; r < 4; r++) {
            int row = m0 + wrM + mi * 16 + lk * 4 + r;
            u16* tp = t + (long)row * 512 + wc + lr;
            #pragma unroll
            for (int nj = 0; nj < 8; nj++)
                tp[nj * 16] = f2bf(acc[mi][nj][r]);
        }
    // ---- fused s1/s2: each wave covers one full head -> 16-lane reduce, direct store
    float a1c[8], a2c[8];
    #pragma unroll
    for (int nj = 0; nj < 8; nj++) {
        int col = nj * 16 + lr;
        a1c[nj] = ag[h * 256 + col];
        a2c[nj] = ag[h * 256 + 128 + col];
    }
    float p1[16], p2[16];
    #pragma unroll
    for (int mi = 0; mi < 4; mi++)
        #pragma unroll
        for (int r = 0; r < 4; r++) {
            float v1 = 0.f, v2 = 0.f;
            #pragma unroll
            for (int nj = 0; nj < 8; nj++) {
                float tv = acc[mi][nj][r];
                v1 += tv * a1c[nj];
                v2 += tv * a2c[nj];
            }
            p1[mi * 4 + r] = v1;
            p2[mi * 4 + r] = v2;
        }
    #pragma unroll
    for (int off = 1; off < 16; off <<= 1)
        #pragma unroll
        for (int i = 0; i < 16; i++) {
            p1[i] += __shfl_xor(p1[i], off, 64);
            p2[i] += __shfl_xor(p2[i], off, 64);
        }
    if (lr == 0) {
        #pragma unroll
        for (int mi = 0; mi < 4; mi++)
            #pragma unroll
            for (int r = 0; r < 4; r++) {
                int row = m0 + wrM + mi * 16 + lk * 4 + r;
                if (row < MROWS) {
                    s1g[(long)row * 4 + h] = p1[mi * 4 + r];
                    s2g[(long)row * 4 + h] = p2[mi * 4 + r];
                }
            }
    }
}

// ---- kernel 3: fused edge pass: score + leaky + exp (no shift; scores |s|<~10)
//      + dst-sorted scatter of srcs/pw + Z block partials, both batches ----
__global__ void edgescatter_kernel(const int* __restrict__ ei, const float* __restrict__ s1,
                                   const float* __restrict__ s2, int* __restrict__ cursor,
                                   int* __restrict__ srcs, float* __restrict__ pw,
                                   float* __restrict__ Zpart) {
    int e = blockIdx.x * 256 + threadIdx.x;
    int tid = threadIdx.x;
    float v[8] = {0.f, 0.f, 0.f, 0.f, 0.f, 0.f, 0.f, 0.f};
    if (e < En) {
        int src = ei[e], dst = ei[En + e];
        #pragma unroll
        for (int b = 0; b < Bn; b++) {
            float4 v1 = *(const float4*)(s1 + ((long)b * Nn + src) * 4);
            float4 v2 = *(const float4*)(s2 + ((long)b * Nn + dst) * 4);
            float s;
            s = v1.x + v2.x; s = s > 0.f ? s : 0.2f * s; v[b * 4 + 0] = __expf(s);
            s = v1.y + v2.y; s = s > 0.f ? s : 0.2f * s; v[b * 4 + 1] = __expf(s);
            s = v1.z + v2.z; s = s > 0.f ? s : 0.2f * s; v[b * 4 + 2] = __expf(s);
            s = v1.w + v2.w; s = s > 0.f ? s : 0.2f * s; v[b * 4 + 3] = __expf(s);
        }
        int pos = atomicAdd(&cursor[dst], 1);
        srcs[pos] = src;
        *(float4*)(pw + (long)pos * 4)        = make_float4(v[0], v[1], v[2], v[3]);
        *(float4*)(pw + ((long)En + pos) * 4) = make_float4(v[4], v[5], v[6], v[7]);
    }
    #pragma unroll
    for (int off = 1; off < 64; off <<= 1)
        #pragma unroll
        for (int i = 0; i < 8; i++)
            v[i] += __shfl_xor(v[i], off, 64);
    __shared__ float red[4][8];
    if ((tid & 63) == 0)
        #pragma unroll
        for (int i = 0; i < 8; i++)
            red[tid >> 6][i] = v[i];
    __syncthreads();
    if (tid < 8)
        Zpart[(long)blockIdx.x * 8 + tid] =
            red[0][tid] + red[1][tid] + red[2][tid] + red[3][tid];
}

// ---- kernel 4: reduce Z partials -> invZ[b*4+h] (256 thr = 8 groups x 32 lanes) ----
__global__ void zreduce_kernel(const float* __restrict__ Zpart, float* __restrict__ invZ) {
    int tid = threadIdx.x;
    int g = tid >> 5, l = tid & 31;
    float s = 0.f;
    for (int i = l; i < EBLK; i += 32)
        s += Zpart[(long)i * 8 + g];
    #pragma unroll
    for (int off = 1; off < 32; off <<= 1)
        s += __shfl_xor(s, off, 64);   // off<32 stays within the 32-lane half
    if (l == 0) invZ[g] = 1.0f / s;
}

// ---- kernel 5: aggregation (no atomics, 2-deep chain, x4 unrolled MLP) + fused LN ----
__launch_bounds__(128)
__global__ void agg_kernel(const u16* __restrict__ t, const int* __restrict__ srcs,
                           const float* __restrict__ pw, const float* __restrict__ invZ,
                           const int* __restrict__ offs,
                           const float* __restrict__ gamma, const float* __restrict__ beta,
                           float* __restrict__ out) {
    int tid = threadIdx.x;               // owns cols 4*tid .. 4*tid+3
    int n = blockIdx.x;
    int b = blockIdx.y;
    int h = tid >> 5;
    int j0 = offs[n], j1 = offs[n + 1];
    const float* pwb = pw + (long)b * En * 4;
    const u16* tb = t + (long)b * Nn * 512;
    float a0 = 0.f, a1 = 0.f, a2 = 0.f, a3 = 0.f;
    int j = j0;
    for (; j + 4 <= j1; j += 4) {
        int s0 = srcs[j], s1i = srcs[j + 1], s2i = srcs[j + 2], s3i = srcs[j + 3];
        float w0 = pwb[(long)j * 4 + h];
        float w1 = pwb[(long)(j + 1) * 4 + h];
        float w2 = pwb[(long)(j + 2) * 4 + h];
        float w3 = pwb[(long)(j + 3) * 4 + h];
        uint2 r0 = *(const uint2*)(tb + (long)s0 * 512 + tid * 4);
        uint2 r1 = *(const uint2*)(tb + (long)s1i * 512 + tid * 4);
        uint2 r2 = *(const uint2*)(tb + (long)s2i * 512 + tid * 4);
        uint2 r3 = *(const uint2*)(tb + (long)s3i * 512 + tid * 4);
        a0 += w0 * bflo(r0.x) + w1 * bflo(r1.x) + w2 * bflo(r2.x) + w3 * bflo(r3.x);
        a1 += w0 * bfhi(r0.x) + w1 * bfhi(r1.x) + w2 * bfhi(r2.x) + w3 * bfhi(r3.x);
        a2 += w0 * bflo(r0.y) + w1 * bflo(r1.y) + w2 * bflo(r2.y) + w3 * bflo(r3.y);
        a3 += w0 * bfhi(r0.y) + w1 * bfhi(r1.y) + w2 * bfhi(r2.y) + w3 * bfhi(r3.y);
    }
    for (; j < j1; j++) {
        int s0 = srcs[j];
        float w0 = pwb[(long)j * 4 + h];
        uint2 r0 = *(const uint2*)(tb + (long)s0 * 512 + tid * 4);
        a0 += w0 * bflo(r0.x);
        a1 += w0 * bfhi(r0.x);
        a2 += w0 * bflo(r0.y);
        a3 += w0 * bfhi(r0.y);
    }
    float invz = invZ[b * 4 + h];
    a0 *= invz; a1 *= invz; a2 *= invz; a3 *= invz;
    // fused LayerNorm over this node's 512 cols (128 threads = 2 waves)
    float s  = a0 + a1 + a2 + a3;
    float ss = a0 * a0 + a1 * a1 + a2 * a2 + a3 * a3;
    #pragma unroll
    for (int off = 1; off < 64; off <<= 1) {
        s  += __shfl_xor(s, off, 64);
        ss += __shfl_xor(ss, off, 64);
    }
    __shared__ float red[2][2];
    int wv = tid >> 6;
    if ((tid & 63) == 0) { red[wv][0] = s; red[wv][1] = ss; }
    __syncthreads();
    s  = red[0][0] + red[1][0];
    ss = red[0][1] + red[1][1];
    float mean = s * (1.0f / 512.0f);
    float var = ss * (1.0f / 512.0f) - mean * mean;
    var = var < 0.f ? 0.f : var;
    float scale = rsqrtf(var + LNEPS);
    int c = tid * 4;
    float4 o;
    o.x = (a0 - mean) * scale * gamma[c + 0] + beta[c + 0];
    o.y = (a1 - mean) * scale * gamma[c + 1] + beta[c + 1];
    o.z = (a2 - mean) * scale * gamma[c + 2] + beta[c + 2];
    o.w = (a3 - mean) * scale * gamma[c + 3] + beta[c + 3];
    *(float4*)(out + ((long)b * Nn + n) * 512 + c) = o;
}

extern "C" void kernel_launch(void* const* d_in, const int* in_sizes, int n_in,
                              void* d_out, int out_size, void* d_ws, size_t ws_size,
                              hipStream_t stream) {
    const float* x     = (const float*)d_in[0];
    const int*   ei    = (const int*)d_in[1];   // (2,E) int32
    const float* W     = (const float*)d_in[2];
    const float* a     = (const float*)d_in[3];
    const float* gamma = (const float*)d_in[4];
    const float* beta  = (const float*)d_in[5];
    float* out = (float*)d_out;

    char* ws = (char*)d_ws;
    size_t off = 0;
    auto alloc = [&](size_t bytes) -> void* {
        void* ptr = ws + off;
        off = (off + bytes + 255) & ~(size_t)255;
        return ptr;
    };
    u16*   xb     = (u16*)alloc((size_t)MPAD * KIN * 2);       // 61.5 MB
    u16*   wbt    = (u16*)alloc((size_t)512 * 512 * 2);        // 0.5 MB
    u16*   t      = (u16*)alloc((size_t)MPAD * 512 * 2);       // 61.5 MB
    float* s1     = (float*)alloc((size_t)MROWS * 4 * 4);
    float* s2     = (float*)alloc((size_t)MROWS * 4 * 4);
    float* pw     = (float*)alloc((size_t)Bn * En * 4 * 4);    // dst-sorted numerators
    float* Zpart  = (float*)alloc((size_t)EBLK * 8 * 4);
    float* invZ   = (float*)alloc(8 * 4);
    int*   deg    = (int*)alloc((size_t)Nn * 4);
    int*   offs   = (int*)alloc((size_t)(Nn + 1) * 4);
    int*   cursor = (int*)alloc((size_t)Nn * 4);
    int*   srcs   = (int*)alloc((size_t)En * 4);

    hipMemsetAsync(deg, 0, (size_t)Nn * 4, stream);

    prep_kernel<<<CVTX_BLKS + CVTW_BLKS + EBLK, 256, 0, stream>>>(x, xb, W, wbt, ei, deg);
    gemm<<<470, 512, 0, stream>>>(xb, wbt, a, t, s1, s2, deg, offs, cursor);
    edgescatter_kernel<<<EBLK, 256, 0, stream>>>(ei, s1, s2, cursor, srcs, pw, Zpart);
    zreduce_kernel<<<1, 256, 0, stream>>>(Zpart, invZ);
    agg_kernel<<<dim3(Nn, Bn), 128, 0, stream>>>(t, srcs, pw, invZ, offs, gamma, beta, out);
}

// Round 5
// 361.209 us; speedup vs baseline: 1.1022x; 1.0974x over previous
//
#include <hip/hip_runtime.h>
#include <stdint.h>

#define Bn 2
#define Nn 30000
#define En 120000
#define KIN 512
#define Hh 4
#define Dd 128
#define MROWS 60000            // B*N rows
#define MPAD  60032            // 469 * 128
#define LNEPS 1e-5f
#define EBLK 469               // ceil(En/256)

typedef unsigned short u16;
typedef unsigned int   u32;
typedef __attribute__((ext_vector_type(8))) short short8;
typedef __attribute__((ext_vector_type(4))) float f32x4;

__device__ __forceinline__ u16 f2bf(float f) {
    u32 u = __builtin_bit_cast(u32, f);
    u32 r = u + 0x7FFFu + ((u >> 16) & 1u);
    return (u16)(r >> 16);
}
__device__ __forceinline__ float bflo(u32 u) {
    return __builtin_bit_cast(float, u << 16);
}
__device__ __forceinline__ float bfhi(u32 u) {
    return __builtin_bit_cast(float, u & 0xFFFF0000u);
}
__device__ __forceinline__ void ld16(void* lds, const void* g) {
    __builtin_amdgcn_global_load_lds((const __attribute__((address_space(1))) void*)g,
                                     (__attribute__((address_space(3))) void*)lds, 16, 0, 0);
}

// ---- kernel 1: prep = cvt_w (1024 blocks) + hist (469).  cvt_x is GONE:
//      the f32->bf16 conversion of x is fused into the gemm's A-staging. ----
#define CVTW_BLKS 1024         // 512*512/256 exactly
__global__ void prep_kernel(const float* __restrict__ W, u16* __restrict__ wbt,
                            const int* __restrict__ ei, int* __restrict__ deg) {
    int blk = blockIdx.x;
    if (blk < CVTW_BLKS) {
        int idx = blk * 256 + threadIdx.x;
        int c = idx >> 9, i = idx & 511;
        int h = c >> 7, d = c & 127;
        wbt[idx] = f2bf(W[h * (KIN * Dd) + i * Dd + d]);
    } else {
        int e = (blk - CVTW_BLKS) * 256 + threadIdx.x;
        if (e < En) atomicAdd(&deg[ei[En + e]], 1);
    }
}

// ---- scan as a device function: 512 threads, exclusive scan of deg[30000].
//      part[] reuses the gemm's LDS block (gemm stays at 80 KB static). ----
__device__ void scan512(const int* __restrict__ deg, int* __restrict__ offs,
                        int* __restrict__ cursor, int* __restrict__ part) {
    int tid = threadIdx.x;
    const int CH = 59;                 // 512*59 = 30208 >= Nn
    int start = tid * CH;
    int s = 0;
    for (int i = 0; i < CH; i++) {
        int n = start + i;
        if (n < Nn) s += deg[n];
    }
    part[tid] = s;
    __syncthreads();
    for (int off = 1; off < 512; off <<= 1) {
        int xv = (tid >= off) ? part[tid - off] : 0;
        __syncthreads();
        part[tid] += xv;
        __syncthreads();
    }
    int run = part[tid] - s;
    for (int i = 0; i < CH; i++) {
        int n = start + i;
        if (n < Nn) {
            offs[n] = run;
            cursor[n] = run;
            run += deg[n];
        }
    }
    if (tid == 511) offs[Nn] = part[511];
}

// ---- kernel 2: GEMM t = x(f32) * wbt^T with FUSED f32->bf16 conversion.
//      A-staging is reg-staged (load f32, cvt, swizzled ds_write_b128);
//      B-staging via global_load_lds (pre-swizzled source, rule #21).
//      Double-buffered, 1 barrier/K-step. 80 KB LDS (scan reuses it).
//      x regs double-buffered (static sets, rule #20): loads issued ~1.5
//      K-steps ahead of their ds_write.
//      8 waves: wave w -> rows (w>>2)*64..+63, head w&3 (cols h*128..+127).
//      Fused s1/s2 epilogue per wave; block 0 hosts the prefix scan. ----
#define A_LDS (2 * 128 * 32)
#define B_LDS (2 * 512 * 32)
__launch_bounds__(512)
__global__ void gemm(const float* __restrict__ x, const u16* __restrict__ wbt,
                     const float* __restrict__ ag, u16* __restrict__ t,
                     float* __restrict__ s1g, float* __restrict__ s2g,
                     const int* __restrict__ deg, int* __restrict__ offs,
                     int* __restrict__ cursor) {
    __shared__ __align__(16) u16 smem[A_LDS + B_LDS];   // 80 KB exactly
    if (blockIdx.x == 0) { scan512(deg, offs, cursor, (int*)smem); return; }
    u16* As0 = smem;
    u16* As1 = smem + 128 * 32;
    u16* Bs0 = smem + A_LDS;
    u16* Bs1 = smem + A_LDS + 512 * 32;
    const int tid = threadIdx.x;
    const int m0 = (blockIdx.x - 1) * 128;          // tiles 0..468
    const int w = tid >> 6, l = tid & 63;
    const int lr = l & 15, lk = l >> 4;
    const int wrM = (w >> 2) * 64;                  // wave row base
    const int h = w & 3;                            // wave head
    const int wc = h * 128;                         // wave col base
    // swizzled ds_read offsets (u16 units): byte ^= ((row&6)<<3) on the 16B slot
    const int swz = (lk * 8) ^ ((lr & 6) << 2);
    int aoff[4], boff[8];
    #pragma unroll
    for (int mi = 0; mi < 4; mi++) aoff[mi] = (wrM + mi * 16 + lr) * 32 + swz;
    #pragma unroll
    for (int nj = 0; nj < 8; nj++) boff[nj] = (wc + nj * 16 + lr) * 32 + swz;

    // A source: thread covers row = tid>>2 (clamped), k-chunk = tid&3 (8 f32)
    const int arow_u = m0 + (tid >> 2);
    const int arow = arow_u < MROWS ? arow_u : (MROWS - 1);   // pad-row clamp
    const float* xsrc = x + (long)arow * KIN + (tid & 3) * 8;
    // swizzled A ds_write address (u16 units), constant across steps
    const int awr = (tid >> 2) * 32 + (((tid & 3) * 8) ^ (((tid >> 2) & 6) << 2));

    // B source: pre-swizzled global (inverse of read swizzle; involution)
    const int grow = tid >> 2, gslot = tid & 3;
    const int gsw = (gslot * 8) ^ ((grow & 6) << 2);
    const u16* bgsrc = wbt + (long)grow * KIN + gsw;   // chunk i = i*512+tid
                                                       // (row += i*128: row&6 unchanged)
    f32x4 acc[4][8] = {};
    float4 a0A, a1A, a0B, a1B;                         // 2 static x-reg sets

#define LOADX(R0, R1, KS)                                           \
    {                                                               \
        R0 = *(const float4*)(xsrc + (KS) * 32);                    \
        R1 = *(const float4*)(xsrc + (KS) * 32 + 4);                \
    }
#define CVTW(BUF, R0, R1)                                           \
    {                                                               \
        short8 o;                                                   \
        o[0] = (short)f2bf(R0.x); o[1] = (short)f2bf(R0.y);         \
        o[2] = (short)f2bf(R0.z); o[3] = (short)f2bf(R0.w);         \
        o[4] = (short)f2bf(R1.x); o[5] = (short)f2bf(R1.y);         \
        o[6] = (short)f2bf(R1.z); o[7] = (short)f2bf(R1.w);         \
        *(short8*)&(BUF)[awr] = o;                                  \
    }

    auto STAGEB = [&](u16* Bb, int k0) {
        #pragma unroll
        for (int i = 0; i < 4; i++)
            ld16(Bb + ((long)(i * 512 + tid)) * 8, bgsrc + (long)i * 128 * KIN + k0);
    };

    // prologue: x(0)->setA, x(1)->setB, B(0) staged, A(0) written
    LOADX(a0A, a1A, 0);
    LOADX(a0B, a1B, 1);
    STAGEB(Bs0, 0);
    CVTW(As0, a0A, a1A);
    __syncthreads();

    #pragma unroll
    for (int t16 = 0; t16 < 16; t16++) {
        u16* Acur = (t16 & 1) ? As1 : As0;
        u16* Bcur = (t16 & 1) ? Bs1 : Bs0;
        u16* Anext = (t16 & 1) ? As0 : As1;
        u16* Bnext = (t16 & 1) ? Bs0 : Bs1;
        if (t16 < 14) {                     // x(t+2) into set (t&1): just freed
            if (t16 & 1) { LOADX(a0B, a1B, t16 + 2); }
            else         { LOADX(a0A, a1A, t16 + 2); }
        }
        if (t16 < 15) STAGEB(Bnext, (t16 + 1) * 32);
        short8 af[4];
        #pragma unroll
        for (int mi = 0; mi < 4; mi++) af[mi] = *(const short8*)&Acur[aoff[mi]];
        #pragma unroll
        for (int nj = 0; nj < 8; nj++) {
            short8 bv = *(const short8*)&Bcur[boff[nj]];
            #pragma unroll
            for (int mi = 0; mi < 4; mi++)
                acc[mi][nj] = __builtin_amdgcn_mfma_f32_16x16x32_bf16(
                    af[mi], bv, acc[mi][nj], 0, 0, 0);
        }
        if (t16 < 15) {                     // write A(t+1) from set ((t+1)&1)
            if (t16 & 1) { CVTW(Anext, a0A, a1A); }
            else         { CVTW(Anext, a0B, a1B); }
        }
        __syncthreads();    // drains staging + protects buffer reuse
    }
#undef LOADX
#undef CVTW

    // C/D map: col = wc + nj*16 + lr, row = wrM + mi*16 + lk*4 + r
    #pragma unroll
    for (int mi = 0; mi < 4; mi++)
        #pragma unroll
        for (int r = 0; r < 4; r++) {
            int row = m0 + wrM + mi * 16 + lk * 4 + r;
            u16* tp = t + (long)row * 512 + wc + lr;
            #pragma unroll
            for (int nj = 0; nj < 8; nj++)
                tp[nj * 16] = f2bf(acc[mi][nj][r]);
        }
    // ---- fused s1/s2: each wave covers one full head -> 16-lane reduce, direct store
    float a1c[8], a2c[8];
    #pragma unroll
    for (int nj = 0; nj < 8; nj++) {
        int col = nj * 16 + lr;
        a1c[nj] = ag[h * 256 + col];
        a2c[nj] = ag[h * 256 + 128 + col];
    }
    float p1[16], p2[16];
    #pragma unroll
    for (int mi = 0; mi < 4; mi++)
        #pragma unroll
        for (int r = 0; r < 4; r++) {
            float v1 = 0.f, v2 = 0.f;
            #pragma unroll
            for (int nj = 0; nj < 8; nj++) {
                float tv = acc[mi][nj][r];
                v1 += tv * a1c[nj];
                v2 += tv * a2c[nj];
            }
            p1[mi * 4 + r] = v1;
            p2[mi * 4 + r] = v2;
        }
    #pragma unroll
    for (int off = 1; off < 16; off <<= 1)
        #pragma unroll
        for (int i = 0; i < 16; i++) {
            p1[i] += __shfl_xor(p1[i], off, 64);
            p2[i] += __shfl_xor(p2[i], off, 64);
        }
    if (lr == 0) {
        #pragma unroll
        for (int mi = 0; mi < 4; mi++)
            #pragma unroll
            for (int r = 0; r < 4; r++) {
                int row = m0 + wrM + mi * 16 + lk * 4 + r;
                if (row < MROWS) {
                    s1g[(long)row * 4 + h] = p1[mi * 4 + r];
                    s2g[(long)row * 4 + h] = p2[mi * 4 + r];
                }
            }
    }
}

// ---- kernel 3: fused edge pass: score + leaky + exp (no shift; scores |s|<~10)
//      + dst-sorted scatter of srcs/pw + Z block partials, both batches ----
__global__ void edgescatter_kernel(const int* __restrict__ ei, const float* __restrict__ s1,
                                   const float* __restrict__ s2, int* __restrict__ cursor,
                                   int* __restrict__ srcs, float* __restrict__ pw,
                                   float* __restrict__ Zpart) {
    int e = blockIdx.x * 256 + threadIdx.x;
    int tid = threadIdx.x;
    float v[8] = {0.f, 0.f, 0.f, 0.f, 0.f, 0.f, 0.f, 0.f};
    if (e < En) {
        int src = ei[e], dst = ei[En + e];
        #pragma unroll
        for (int b = 0; b < Bn; b++) {
            float4 v1 = *(const float4*)(s1 + ((long)b * Nn + src) * 4);
            float4 v2 = *(const float4*)(s2 + ((long)b * Nn + dst) * 4);
            float s;
            s = v1.x + v2.x; s = s > 0.f ? s : 0.2f * s; v[b * 4 + 0] = __expf(s);
            s = v1.y + v2.y; s = s > 0.f ? s : 0.2f * s; v[b * 4 + 1] = __expf(s);
            s = v1.z + v2.z; s = s > 0.f ? s : 0.2f * s; v[b * 4 + 2] = __expf(s);
            s = v1.w + v2.w; s = s > 0.f ? s : 0.2f * s; v[b * 4 + 3] = __expf(s);
        }
        int pos = atomicAdd(&cursor[dst], 1);
        srcs[pos] = src;
        *(float4*)(pw + (long)pos * 4)        = make_float4(v[0], v[1], v[2], v[3]);
        *(float4*)(pw + ((long)En + pos) * 4) = make_float4(v[4], v[5], v[6], v[7]);
    }
    #pragma unroll
    for (int off = 1; off < 64; off <<= 1)
        #pragma unroll
        for (int i = 0; i < 8; i++)
            v[i] += __shfl_xor(v[i], off, 64);
    __shared__ float red[4][8];
    if ((tid & 63) == 0)
        #pragma unroll
        for (int i = 0; i < 8; i++)
            red[tid >> 6][i] = v[i];
    __syncthreads();
    if (tid < 8)
        Zpart[(long)blockIdx.x * 8 + tid] =
            red[0][tid] + red[1][tid] + red[2][tid] + red[3][tid];
}

// ---- kernel 4: reduce Z partials -> invZ[b*4+h] (256 thr = 8 groups x 32 lanes) ----
__global__ void zreduce_kernel(const float* __restrict__ Zpart, float* __restrict__ invZ) {
    int tid = threadIdx.x;
    int g = tid >> 5, l = tid & 31;
    float s = 0.f;
    for (int i = l; i < EBLK; i += 32)
        s += Zpart[(long)i * 8 + g];
    #pragma unroll
    for (int off = 1; off < 32; off <<= 1)
        s += __shfl_xor(s, off, 64);   // off<32 stays within the 32-lane half
    if (l == 0) invZ[g] = 1.0f / s;
}

// ---- kernel 5: aggregation, BOTH batches per block (256 thr = 2x128),
//      no atomics, x4 unrolled, fused LN. Halves block count; doubles
//      loads-in-flight per block; amortizes offs/srcs. ----
__launch_bounds__(256)
__global__ void agg_kernel(const u16* __restrict__ t, const int* __restrict__ srcs,
                           const float* __restrict__ pw, const float* __restrict__ invZ,
                           const int* __restrict__ offs,
                           const float* __restrict__ gamma, const float* __restrict__ beta,
                           float* __restrict__ out) {
    int tid = threadIdx.x;
    int b = tid >> 7;                    // batch = upper/lower half of block
    int lt = tid & 127;                  // owns cols 4*lt .. 4*lt+3
    int n = blockIdx.x;
    int h = lt >> 5;
    int j0 = offs[n], j1 = offs[n + 1];
    const float* pwb = pw + (long)b * En * 4;
    const u16* tb = t + (long)b * Nn * 512;
    float a0 = 0.f, a1 = 0.f, a2 = 0.f, a3 = 0.f;
    int j = j0;
    for (; j + 4 <= j1; j += 4) {
        int s0 = srcs[j], s1i = srcs[j + 1], s2i = srcs[j + 2], s3i = srcs[j + 3];
        float w0 = pwb[(long)j * 4 + h];
        float w1 = pwb[(long)(j + 1) * 4 + h];
        float w2 = pwb[(long)(j + 2) * 4 + h];
        float w3 = pwb[(long)(j + 3) * 4 + h];
        uint2 r0 = *(const uint2*)(tb + (long)s0 * 512 + lt * 4);
        uint2 r1 = *(const uint2*)(tb + (long)s1i * 512 + lt * 4);
        uint2 r2 = *(const uint2*)(tb + (long)s2i * 512 + lt * 4);
        uint2 r3 = *(const uint2*)(tb + (long)s3i * 512 + lt * 4);
        a0 += w0 * bflo(r0.x) + w1 * bflo(r1.x) + w2 * bflo(r2.x) + w3 * bflo(r3.x);
        a1 += w0 * bfhi(r0.x) + w1 * bfhi(r1.x) + w2 * bfhi(r2.x) + w3 * bfhi(r3.x);
        a2 += w0 * bflo(r0.y) + w1 * bflo(r1.y) + w2 * bflo(r2.y) + w3 * bflo(r3.y);
        a3 += w0 * bfhi(r0.y) + w1 * bfhi(r1.y) + w2 * bfhi(r2.y) + w3 * bfhi(r3.y);
    }
    for (; j < j1; j++) {
        int s0 = srcs[j];
        float w0 = pwb[(long)j * 4 + h];
        uint2 r0 = *(const uint2*)(tb + (long)s0 * 512 + lt * 4);
        a0 += w0 * bflo(r0.x);
        a1 += w0 * bfhi(r0.x);
        a2 += w0 * bflo(r0.y);
        a3 += w0 * bfhi(r0.y);
    }
    float invz = invZ[b * 4 + h];
    a0 *= invz; a1 *= invz; a2 *= invz; a3 *= invz;
    // fused LayerNorm over this (b,n)'s 512 cols (128 threads = 2 waves/half)
    float s  = a0 + a1 + a2 + a3;
    float ss = a0 * a0 + a1 * a1 + a2 * a2 + a3 * a3;
    #pragma unroll
    for (int off = 1; off < 64; off <<= 1) {
        s  += __shfl_xor(s, off, 64);
        ss += __shfl_xor(ss, off, 64);
    }
    __shared__ float red[4][2];          // per wave; waves 0-1 = b0, 2-3 = b1
    int wv = tid >> 6;
    if ((tid & 63) == 0) { red[wv][0] = s; red[wv][1] = ss; }
    __syncthreads();
    s  = red[b * 2][0] + red[b * 2 + 1][0];
    ss = red[b * 2][1] + red[b * 2 + 1][1];
    float mean = s * (1.0f / 512.0f);
    float var = ss * (1.0f / 512.0f) - mean * mean;
    var = var < 0.f ? 0.f : var;
    float scale = rsqrtf(var + LNEPS);
    int c = lt * 4;
    float4 o;
    o.x = (a0 - mean) * scale * gamma[c + 0] + beta[c + 0];
    o.y = (a1 - mean) * scale * gamma[c + 1] + beta[c + 1];
    o.z = (a2 - mean) * scale * gamma[c + 2] + beta[c + 2];
    o.w = (a3 - mean) * scale * gamma[c + 3] + beta[c + 3];
    *(float4*)(out + ((long)b * Nn + n) * 512 + c) = o;
}

extern "C" void kernel_launch(void* const* d_in, const int* in_sizes, int n_in,
                              void* d_out, int out_size, void* d_ws, size_t ws_size,
                              hipStream_t stream) {
    const float* x     = (const float*)d_in[0];
    const int*   ei    = (const int*)d_in[1];   // (2,E) int32
    const float* W     = (const float*)d_in[2];
    const float* a     = (const float*)d_in[3];
    const float* gamma = (const float*)d_in[4];
    const float* beta  = (const float*)d_in[5];
    float* out = (float*)d_out;

    char* ws = (char*)d_ws;
    size_t off = 0;
    auto alloc = [&](size_t bytes) -> void* {
        void* ptr = ws + off;
        off = (off + bytes + 255) & ~(size_t)255;
        return ptr;
    };
    u16*   wbt    = (u16*)alloc((size_t)512 * 512 * 2);        // 0.5 MB
    u16*   t      = (u16*)alloc((size_t)MPAD * 512 * 2);       // 61.5 MB
    float* s1     = (float*)alloc((size_t)MROWS * 4 * 4);
    float* s2     = (float*)alloc((size_t)MROWS * 4 * 4);
    float* pw     = (float*)alloc((size_t)Bn * En * 4 * 4);    // dst-sorted numerators
    float* Zpart  = (float*)alloc((size_t)EBLK * 8 * 4);
    float* invZ   = (float*)alloc(8 * 4);
    int*   deg    = (int*)alloc((size_t)Nn * 4);
    int*   offs   = (int*)alloc((size_t)(Nn + 1) * 4);
    int*   cursor = (int*)alloc((size_t)Nn * 4);
    int*   srcs   = (int*)alloc((size_t)En * 4);

    hipMemsetAsync(deg, 0, (size_t)Nn * 4, stream);

    prep_kernel<<<CVTW_BLKS + EBLK, 256, 0, stream>>>(W, wbt, ei, deg);
    gemm<<<470, 512, 0, stream>>>(x, wbt, a, t, s1, s2, deg, offs, cursor);
    edgescatter_kernel<<<EBLK, 256, 0, stream>>>(ei, s1, s2, cursor, srcs, pw, Zpart);
    zreduce_kernel<<<1, 256, 0, stream>>>(Zpart, invZ);
    agg_kernel<<<Nn, 256, 0, stream>>>(t, srcs, pw, invZ, offs, gamma, beta, out);
}